// Round 5
// baseline (121.830 us; speedup 1.0000x reference)
//
#include <hip/hip_runtime.h>
#include <hip/hip_bf16.h>

// Problem constants
#define D_DIM 512
#define K_DIM 512
#define B_C   64
#define LMAX_C 1024

// Tile config: 256x256 block tile, 8 waves (2 wave-rows x 4 wave-cols)
#define BM 256
#define BN 256
#define BK 64
#define KSTEPS 8             // D_DIM / BK
#define ROWT 4               // LMAX / BM
#define COLT 2               // K_DIM / BN
#define NWG  (B_C * ROWT * COLT)   // 512, divisible by 8 XCDs

typedef __attribute__((ext_vector_type(8))) short bf16x8;
typedef __attribute__((ext_vector_type(4))) float f32x4;

__device__ __forceinline__ short f2bf(float f) {
    union { __hip_bfloat16 h; short s; } u;
    u.h = __float2bfloat16(f);
    return u.s;
}

// LDS swizzle (validated zero-conflict in R3). Row stride = 128B (64 bf16).
// 16B-granular XOR: f(r) = ((r&7) ^ ((r>>2)&7)) << 4
__device__ __forceinline__ short* lds_addr(short* base, int row, int kbyte) {
    return (short*)((char*)base + row * 128 +
                    (kbyte ^ ((((row & 7) ^ ((row >> 2) & 7))) << 4)));
}

__global__ __launch_bounds__(512, 2) void jbmm_kernel(
    const int* __restrict__ offsets,   // B+1
    const int* __restrict__ index,     // B
    const float* __restrict__ jagged,  // T x D
    const float* __restrict__ weight,  // NW x D x K
    const float* __restrict__ bias,    // NW x K
    float* __restrict__ out)           // T x K
{
    // A: 256 rows x 64 k (bf16) = 32KB/buf; B: 64 k x 256 n transposed = 32KB/buf
    __shared__ short As[2][BM * BK];
    __shared__ short Bs[2][BN * BK];

    // XCD chunk swizzle (512 % 8 == 0 -> bijective)
    const int bidRaw = blockIdx.x;
    const int bid = (bidRaw & 7) * (NWG / 8) + (bidRaw >> 3);

    const int b   = bid / (ROWT * COLT);
    const int rt  = (bid / COLT) % ROWT;
    const int ct  = bid % COLT;

    const int start = offsets[b];
    const int end   = offsets[b + 1];
    const int m0    = start + rt * BM;
    if (m0 >= end) return;
    const int rows = (end - m0) < BM ? (end - m0) : BM;

    const int idxw = index[b];
    const float* W = weight + (size_t)idxw * D_DIM * K_DIM;
    const int n0 = ct * BN;

    const int tid  = threadIdx.x;
    const int lane = tid & 63;
    const int wid  = tid >> 6;   // 0..7
    const int wr   = wid >> 2;   // 0..1  wave row (128 rows each)
    const int wc   = wid & 3;    // 0..3  wave col (64 cols each)
    const int lr   = lane & 15;
    const int lg   = lane >> 4;

    // staging maps (512 threads)
    // A: row = tid>>1 (0..255), k-half = tid&1 -> 32 consecutive floats
    const int arow  = tid >> 1;
    const int ahalf = tid & 1;
    // B: n-quad = lane (n = 4*lane..), k-octet = wid -> 8 k-rows x 4 n
    const int nq  = tid & 63;
    const int ko8 = tid >> 6;

    float bias_v[4];
#pragma unroll
    for (int ni = 0; ni < 4; ++ni)
        bias_v[ni] = bias[(size_t)idxw * K_DIM + n0 + wc * 64 + ni * 16 + lr];

    f32x4 acc[8][4];
#pragma unroll
    for (int mi = 0; mi < 8; ++mi)
#pragma unroll
        for (int ni = 0; ni < 4; ++ni)
            acc[mi][ni] = (f32x4){0.f, 0.f, 0.f, 0.f};

    f32x4 aR[8];   // A: 32 consecutive floats of one row
    f32x4 bR[8];   // B: 8 k-rows x 4 n

#define LOADA(k0_)                                                          \
    {                                                                       \
        if (arow < rows) {                                                  \
            const float* p = &jagged[(size_t)(m0 + arow) * D_DIM + (k0_) + ahalf * 32]; \
            _Pragma("unroll")                                               \
            for (int j = 0; j < 8; ++j)                                     \
                aR[j] = *reinterpret_cast<const f32x4*>(p + 4 * j);         \
        } else {                                                            \
            _Pragma("unroll")                                               \
            for (int j = 0; j < 8; ++j)                                     \
                aR[j] = (f32x4){0.f, 0.f, 0.f, 0.f};                        \
        }                                                                   \
    }

#define LOADB(k0_)                                                          \
    {                                                                       \
        _Pragma("unroll")                                                   \
        for (int j = 0; j < 8; ++j)                                         \
            bR[j] = *reinterpret_cast<const f32x4*>(                        \
                &W[(size_t)((k0_) + ko8 * 8 + j) * K_DIM + n0 + nq * 4]);   \
    }

#define CVTSTORE(c_)                                                        \
    {                                                                       \
        _Pragma("unroll")                                                   \
        for (int q = 0; q < 4; ++q) {                                       \
            bf16x8 w;                                                       \
            w[0] = f2bf(aR[2*q][0]); w[1] = f2bf(aR[2*q][1]);               \
            w[2] = f2bf(aR[2*q][2]); w[3] = f2bf(aR[2*q][3]);               \
            w[4] = f2bf(aR[2*q+1][0]); w[5] = f2bf(aR[2*q+1][1]);           \
            w[6] = f2bf(aR[2*q+1][2]); w[7] = f2bf(aR[2*q+1][3]);           \
            *reinterpret_cast<bf16x8*>(                                     \
                lds_addr(&As[c_][0], arow, ahalf * 64 + q * 16)) = w;       \
        }                                                                   \
        _Pragma("unroll")                                                   \
        for (int np = 0; np < 4; ++np) {                                    \
            bf16x8 w;                                                       \
            w[0] = f2bf(bR[0][np]); w[1] = f2bf(bR[1][np]);                 \
            w[2] = f2bf(bR[2][np]); w[3] = f2bf(bR[3][np]);                 \
            w[4] = f2bf(bR[4][np]); w[5] = f2bf(bR[5][np]);                 \
            w[6] = f2bf(bR[6][np]); w[7] = f2bf(bR[7][np]);                 \
            *reinterpret_cast<bf16x8*>(                                     \
                lds_addr(&Bs[c_][0], nq * 4 + np, ko8 * 16)) = w;           \
        }                                                                   \
    }

#define COMPUTE(c_)                                                         \
    {                                                                       \
        _Pragma("unroll")                                                   \
        for (int kh = 0; kh < 2; ++kh) {                                    \
            bf16x8 bfr[4];                                                  \
            _Pragma("unroll")                                               \
            for (int ni = 0; ni < 4; ++ni)                                  \
                bfr[ni] = *reinterpret_cast<bf16x8*>(                       \
                    lds_addr(&Bs[c_][0], wc * 64 + ni * 16 + lr, kh * 64 + lg * 16)); \
            _Pragma("unroll")                                               \
            for (int mi = 0; mi < 8; ++mi) {                                \
                bf16x8 af = *reinterpret_cast<bf16x8*>(                     \
                    lds_addr(&As[c_][0], wr * 128 + mi * 16 + lr, kh * 64 + lg * 16)); \
                _Pragma("unroll")                                           \
                for (int ni = 0; ni < 4; ++ni)                              \
                    acc[mi][ni] = __builtin_amdgcn_mfma_f32_16x16x32_bf16(  \
                        af, bfr[ni], acc[mi][ni], 0, 0, 0);                 \
            }                                                               \
        }                                                                   \
    }

    // ---- prologue: fill buffer 0 ----
    LOADA(0); LOADB(0);
    CVTSTORE(0);
    __syncthreads();

    // ---- main loop: loads at top (drain-free barrier), consume at bottom ----
#pragma unroll
    for (int t = 0; t < KSTEPS; ++t) {
        if (t + 1 < KSTEPS) {
            const int kn = (t + 1) * BK;
            LOADA(kn); LOADB(kn);      // in flight across COMPUTE
        }
        COMPUTE(t & 1);
        if (t + 1 < KSTEPS) {
            CVTSTORE((t + 1) & 1);     // vmcnt wait covered by COMPUTE above
            __syncthreads();
        }
    }

    // ---- epilogue: C/D layout col=lane&15, row=(lane>>4)*4+r ----
#pragma unroll
    for (int mi = 0; mi < 8; ++mi) {
        const int rloc = wr * 128 + mi * 16 + lg * 4;
#pragma unroll
        for (int r = 0; r < 4; ++r) {
            const int rr = rloc + r;
            if (rr < rows) {
#pragma unroll
                for (int ni = 0; ni < 4; ++ni) {
                    out[(size_t)(m0 + rr) * K_DIM + n0 + wc * 64 + ni * 16 + lr] =
                        acc[mi][ni][r] + bias_v[ni];
                }
            }
        }
    }
}

extern "C" void kernel_launch(void* const* d_in, const int* in_sizes, int n_in,
                              void* d_out, int out_size, void* d_ws, size_t ws_size,
                              hipStream_t stream) {
    const int*   offsets = (const int*)d_in[1];
    const int*   index   = (const int*)d_in[2];
    const float* jagged  = (const float*)d_in[3];
    const float* weight  = (const float*)d_in[4];
    const float* bias    = (const float*)d_in[5];
    float*       out     = (float*)d_out;

    dim3 grid(NWG);
    dim3 block(512);
    hipLaunchKernelGGL(jbmm_kernel, grid, block, 0, stream,
                       offsets, index, jagged, weight, bias, out);
}

// Round 6
// 46.564 us; speedup vs baseline: 2.6164x; 2.6164x over previous
//
#include <hip/hip_runtime.h>
#include <hip/hip_bf16.h>

// Problem constants
#define D_DIM 512
#define K_DIM 512
#define B_C   64
#define LMAX_C 1024

// Tile config (R3-validated): 128x128 tile, 4 waves (2x2), BK=64
#define BM 128
#define BN 128
#define BK 64
#define KSTEPS 8             // D_DIM / BK
#define ROWT 8               // LMAX / BM
#define COLT 4               // K_DIM / BN
#define NWG  (B_C * ROWT * COLT)   // 2048, divisible by 8 XCDs

typedef __attribute__((ext_vector_type(8))) short bf16x8;
typedef __attribute__((ext_vector_type(4))) float f32x4;

__device__ __forceinline__ short f2bf(float f) {
    union { __hip_bfloat16 h; short s; } u;
    u.h = __float2bfloat16(f);
    return u.s;
}

// LDS swizzle (validated zero-conflict in R3). Row stride = 128B (64 bf16).
// 16B-granular XOR: f(r) = ((r&7) ^ ((r>>2)&7)) << 4
__device__ __forceinline__ short* lds_addr(short* base, int row, int kbyte) {
    return (short*)((char*)base + row * 128 +
                    (kbyte ^ ((((row & 7) ^ ((row >> 2) & 7))) << 4)));
}

__global__ __launch_bounds__(256, 2) void jbmm_kernel(
    const int* __restrict__ offsets,   // B+1
    const int* __restrict__ index,     // B
    const float* __restrict__ jagged,  // T x D
    const float* __restrict__ weight,  // NW x D x K
    const float* __restrict__ bias,    // NW x K
    float* __restrict__ out)           // T x K
{
    // double-buffered: exactly 64 KiB total
    __shared__ short As[2][BM * BK];
    __shared__ short Bs[2][BN * BK];

    // XCD chunk swizzle (2048 % 8 == 0 -> bijective)
    const int bidRaw = blockIdx.x;
    const int bid = (bidRaw & 7) * (NWG / 8) + (bidRaw >> 3);

    const int b   = bid / (ROWT * COLT);
    const int rt  = (bid / COLT) % ROWT;
    const int ct  = bid % COLT;

    const int start = offsets[b];
    const int end   = offsets[b + 1];
    const int m0    = start + rt * BM;
    if (m0 >= end) return;
    const int rows = (end - m0) < BM ? (end - m0) : BM;

    const int idxw = index[b];
    const float* W = weight + (size_t)idxw * D_DIM * K_DIM;
    const int n0 = ct * BN;

    const int tid  = threadIdx.x;
    const int lane = tid & 63;
    const int wid  = tid >> 6;
    const int wr   = wid >> 1;   // wave row (2x2)
    const int wc   = wid & 1;    // wave col
    const int lr   = lane & 15;
    const int lg   = lane >> 4;

    // staging maps
    const int arow  = tid >> 3;  // 0..31 (+32*i)
    const int acol8 = tid & 7;   // 0..7  -> k-octet
    const int n4    = tid & 31;  // 0..31 -> n-quad (rows 4*n4..+3)
    const int dq8   = tid >> 5;  // 0..7  -> k-octet for B

    float bias_v[4];
#pragma unroll
    for (int ni = 0; ni < 4; ++ni)
        bias_v[ni] = bias[(size_t)idxw * K_DIM + n0 + wc * 64 + ni * 16 + lr];

    f32x4 acc[4][4];
#pragma unroll
    for (int mi = 0; mi < 4; ++mi)
#pragma unroll
        for (int ni = 0; ni < 4; ++ni)
            acc[mi][ni] = (f32x4){0.f, 0.f, 0.f, 0.f};

    f32x4 aR[8];   // A: 4 rows x 32B
    f32x4 bR[8];   // B: 8 k-rows x 16B (4 n)

#define LOADA(k0_)                                                          \
    {                                                                       \
        _Pragma("unroll")                                                   \
        for (int i = 0; i < 4; ++i) {                                       \
            const int r = arow + 32 * i;                                    \
            f32x4 v0 = (f32x4){0.f,0.f,0.f,0.f};                            \
            f32x4 v1 = (f32x4){0.f,0.f,0.f,0.f};                            \
            if (r < rows) {                                                 \
                const float* p = &jagged[(size_t)(m0 + r) * D_DIM + (k0_) + acol8 * 8]; \
                v0 = *reinterpret_cast<const f32x4*>(p);                    \
                v1 = *reinterpret_cast<const f32x4*>(p + 4);                \
            }                                                               \
            aR[2 * i] = v0; aR[2 * i + 1] = v1;                             \
        }                                                                   \
    }

#define LOADB(k0_)                                                          \
    {                                                                       \
        _Pragma("unroll")                                                   \
        for (int j = 0; j < 8; ++j)                                         \
            bR[j] = *reinterpret_cast<const f32x4*>(                        \
                &W[(size_t)((k0_) + dq8 * 8 + j) * K_DIM + n0 + n4 * 4]);   \
    }

#define CVTSTORE(c_)                                                        \
    {                                                                       \
        _Pragma("unroll")                                                   \
        for (int i = 0; i < 4; ++i) {                                       \
            const int r = arow + 32 * i;                                    \
            bf16x8 w;                                                       \
            w[0] = f2bf(aR[2*i][0]); w[1] = f2bf(aR[2*i][1]);               \
            w[2] = f2bf(aR[2*i][2]); w[3] = f2bf(aR[2*i][3]);               \
            w[4] = f2bf(aR[2*i+1][0]); w[5] = f2bf(aR[2*i+1][1]);           \
            w[6] = f2bf(aR[2*i+1][2]); w[7] = f2bf(aR[2*i+1][3]);           \
            *reinterpret_cast<bf16x8*>(lds_addr(&As[c_][0], r, acol8 * 16)) = w; \
        }                                                                   \
        _Pragma("unroll")                                                   \
        for (int np = 0; np < 4; ++np) {                                    \
            bf16x8 w;                                                       \
            w[0] = f2bf(bR[0][np]); w[1] = f2bf(bR[1][np]);                 \
            w[2] = f2bf(bR[2][np]); w[3] = f2bf(bR[3][np]);                 \
            w[4] = f2bf(bR[4][np]); w[5] = f2bf(bR[5][np]);                 \
            w[6] = f2bf(bR[6][np]); w[7] = f2bf(bR[7][np]);                 \
            *reinterpret_cast<bf16x8*>(lds_addr(&Bs[c_][0], n4 * 4 + np, dq8 * 16)) = w; \
        }                                                                   \
    }

#define COMPUTE(c_)                                                         \
    {                                                                       \
        __builtin_amdgcn_s_setprio(1);                                      \
        _Pragma("unroll")                                                   \
        for (int kh = 0; kh < 2; ++kh) {                                    \
            bf16x8 af[4], bfr[4];                                           \
            _Pragma("unroll")                                               \
            for (int mi = 0; mi < 4; ++mi)                                  \
                af[mi] = *reinterpret_cast<bf16x8*>(                        \
                    lds_addr(&As[c_][0], wr * 64 + mi * 16 + lr, kh * 64 + lg * 16)); \
            _Pragma("unroll")                                               \
            for (int ni = 0; ni < 4; ++ni)                                  \
                bfr[ni] = *reinterpret_cast<bf16x8*>(                       \
                    lds_addr(&Bs[c_][0], wc * 64 + ni * 16 + lr, kh * 64 + lg * 16)); \
            _Pragma("unroll")                                               \
            for (int mi = 0; mi < 4; ++mi)                                  \
                _Pragma("unroll")                                           \
                for (int ni = 0; ni < 4; ++ni)                              \
                    acc[mi][ni] = __builtin_amdgcn_mfma_f32_16x16x32_bf16(  \
                        af[mi], bfr[ni], acc[mi][ni], 0, 0, 0);             \
        }                                                                   \
        __builtin_amdgcn_s_setprio(0);                                      \
    }

// Raw barrier WITHOUT vmcnt drain: only LDS ops must be complete.
// Global loads (into private registers) legitimately stay in flight.
#define BARRIER_LDS()                                                       \
    {                                                                       \
        asm volatile("s_waitcnt lgkmcnt(0)" ::: "memory");                  \
        __builtin_amdgcn_s_barrier();                                       \
        asm volatile("" ::: "memory");                                      \
    }

    // ---- prologue: fill buffer 0 ----
    LOADA(0); LOADB(0);
    CVTSTORE(0);
    BARRIER_LDS();

    // ---- main loop: loads issued at top survive the barrier (counted vmcnt) ----
#pragma unroll
    for (int t = 0; t < KSTEPS; ++t) {
        if (t + 1 < KSTEPS) {
            const int kn = (t + 1) * BK;
            LOADA(kn); LOADB(kn);      // in flight across COMPUTE; no drain at barrier
        }
        COMPUTE(t & 1);
        if (t + 1 < KSTEPS) {
            CVTSTORE((t + 1) & 1);     // vmcnt wait (precise) covered by COMPUTE above
            BARRIER_LDS();
        }
    }

    // ---- epilogue: C/D layout col=lane&15, row=(lane>>4)*4+r ----
#pragma unroll
    for (int mi = 0; mi < 4; ++mi) {
        const int rloc = wr * 64 + mi * 16 + lg * 4;
#pragma unroll
        for (int r = 0; r < 4; ++r) {
            const int rr = rloc + r;
            if (rr < rows) {
#pragma unroll
                for (int ni = 0; ni < 4; ++ni) {
                    out[(size_t)(m0 + rr) * K_DIM + n0 + wc * 64 + ni * 16 + lr] =
                        acc[mi][ni][r] + bias_v[ni];
                }
            }
        }
    }
}

extern "C" void kernel_launch(void* const* d_in, const int* in_sizes, int n_in,
                              void* d_out, int out_size, void* d_ws, size_t ws_size,
                              hipStream_t stream) {
    const int*   offsets = (const int*)d_in[1];
    const int*   index   = (const int*)d_in[2];
    const float* jagged  = (const float*)d_in[3];
    const float* weight  = (const float*)d_in[4];
    const float* bias    = (const float*)d_in[5];
    float*       out     = (float*)d_out;

    dim3 grid(NWG);
    dim3 block(256);
    hipLaunchKernelGGL(jbmm_kernel, grid, block, 0, stream,
                       offsets, index, jagged, weight, bias, out);
}